// Round 1
// baseline (6116.537 us; speedup 1.0000x reference)
//
#include <hip/hip_runtime.h>
#include <hip/hip_bf16.h>

// Problem constants
#define BB 64     // batch
#define TT 512    // seq len
#define EE 512    // embed dim
#define HH 512    // hidden
#define G4 2048   // 4*H

// ---------------- K0: transpose Wh [512][2048] -> WhT [2048][512] ----------------
__global__ __launch_bounds__(256) void k0_transpose(const float* __restrict__ W,
                                                    float* __restrict__ WT) {
    __shared__ float tile[32][33];
    int gx = blockIdx.x * 32;           // gate-col dim (2048)
    int ky = blockIdx.y * 32;           // k dim (512)
    int tx = threadIdx.x & 31, ty = threadIdx.x >> 5;   // 32 x 8
    #pragma unroll
    for (int i = 0; i < 32; i += 8)
        tile[ty + i][tx] = W[(size_t)(ky + ty + i) * G4 + gx + tx];
    __syncthreads();
    #pragma unroll
    for (int i = 0; i < 32; i += 8)
        WT[(size_t)(gx + ty + i) * HH + ky + tx] = tile[tx][ty + i];
}

// ---------------- K1: xp[t][b][g] = emb[words[b][t]] @ Wi + bi  (bf16 out) -------
// Tile 128x128, BK=16, 256 threads, 8x8 micro-tile.
__global__ __launch_bounds__(256) void k1_xp(const int* __restrict__ words,
                                             const float* __restrict__ emb,
                                             const float* __restrict__ Wi,
                                             const float* __restrict__ bi,
                                             __hip_bfloat16* __restrict__ xp) {
    __shared__ float As[16][136];    // [k][m]  (136: pad, 544B rows, 16B aligned)
    __shared__ float Bs[16][136];    // [k][n]
    __shared__ int wrow[128];
    const int tid = threadIdx.x;
    const int by = blockIdx.y;       // m-tile (rows by*128..)
    const int bx = blockIdx.x;       // n-tile
    if (tid < 128) {
        int m = by * 128 + tid;
        int t = m >> 6, b = m & 63;
        wrow[tid] = words[b * TT + t];
    }
    __syncthreads();
    float acc[8][8] = {};
    const int tx = tid & 15, ty = tid >> 4;
    for (int k0 = 0; k0 < EE; k0 += 16) {
        #pragma unroll
        for (int q = 0; q < 2; ++q) {
            int idx = tid * 2 + q;                 // 0..511
            int r = idx >> 2, seg = idx & 3;       // A: 128 rows x 4 float4
            float4 av = *(const float4*)&emb[(size_t)wrow[r] * EE + k0 + seg * 4];
            As[seg * 4 + 0][r] = av.x; As[seg * 4 + 1][r] = av.y;
            As[seg * 4 + 2][r] = av.z; As[seg * 4 + 3][r] = av.w;
            int kk = idx >> 5, j4 = idx & 31;      // B: 16 rows x 32 float4
            float4 bv = *(const float4*)&Wi[(size_t)(k0 + kk) * G4 + bx * 128 + j4 * 4];
            *(float4*)&Bs[kk][j4 * 4] = bv;
        }
        __syncthreads();
        #pragma unroll
        for (int k = 0; k < 16; ++k) {
            float a[8], bb[8];
            *(float4*)&a[0] = *(const float4*)&As[k][ty * 8];
            *(float4*)&a[4] = *(const float4*)&As[k][ty * 8 + 4];
            *(float4*)&bb[0] = *(const float4*)&Bs[k][tx * 8];
            *(float4*)&bb[4] = *(const float4*)&Bs[k][tx * 8 + 4];
            #pragma unroll
            for (int i = 0; i < 8; ++i)
                #pragma unroll
                for (int j = 0; j < 8; ++j) acc[i][j] += a[i] * bb[j];
        }
        __syncthreads();
    }
    #pragma unroll
    for (int i = 0; i < 8; ++i) {
        int m = by * 128 + ty * 8 + i;
        int t = m >> 6, b = m & 63;
        __hip_bfloat16* row = xp + ((size_t)t * BB + b) * G4 + bx * 128 + tx * 8;
        #pragma unroll
        for (int j = 0; j < 8; ++j) {
            float v = acc[i][j] + bi[bx * 128 + tx * 8 + j];
            row[j] = __float2bfloat16(v);
        }
    }
}

// ---------------- K2: one LSTM time step ----------------------------------------
// grid (64,8): blockIdx.x = unit-block (8 hidden units), blockIdx.y = batch-group (8 b)
// 256 threads: thread = (cloc 0..31 [gate-col within WG], bl 0..7 [batch within group])
__global__ __launch_bounds__(256) void k2_step(const float* __restrict__ WhT,
                                               const __hip_bfloat16* __restrict__ xp,
                                               const float* __restrict__ bh,
                                               float* __restrict__ hs,
                                               float* __restrict__ cstate, int t) {
    const int ub = blockIdx.x;   // 0..63
    const int bg = blockIdx.y;   // 0..7
    const int tid = threadIdx.x;
    __shared__ float hbuf[8][520];   // h_prev for 8 batches (pad 520: 2-way only)
    __shared__ float gbuf[32][9];
    if (t == 0) {
        #pragma unroll
        for (int q = 0; q < 4; ++q) {
            int idx = tid + q * 256;
            int b2 = idx >> 7, k4 = idx & 127;
            *(float4*)&hbuf[b2][k4 * 4] = make_float4(0.f, 0.f, 0.f, 0.f);
        }
    } else {
        const float* hprev = hs + ((size_t)(t - 1) * BB + bg * 8) * HH;
        #pragma unroll
        for (int q = 0; q < 4; ++q) {
            int idx = tid + q * 256;
            int b2 = idx >> 7, k4 = idx & 127;
            *(float4*)&hbuf[b2][k4 * 4] = *(const float4*)&hprev[(size_t)b2 * HH + k4 * 4];
        }
    }
    const int cloc = tid >> 3;                 // 0..31
    const int bl = tid & 7;                    // 0..7
    const int g = cloc >> 3, uoff = cloc & 7;
    const int gcol = g * HH + ub * 8 + uoff;   // global gate column
    const int bglob = bg * 8 + bl;
    float xv = __bfloat162float(xp[((size_t)t * BB + bglob) * G4 + gcol]);
    float bhv = bh[gcol];
    __syncthreads();
    const float* wp = WhT + (size_t)gcol * HH;
    float acc = 0.f;
    #pragma unroll 4
    for (int k4 = 0; k4 < 128; ++k4) {
        float4 w = *(const float4*)&wp[k4 * 4];
        float4 h = *(const float4*)&hbuf[bl][k4 * 4];
        acc += w.x * h.x + w.y * h.y + w.z * h.z + w.w * h.w;
    }
    gbuf[cloc][bl] = acc + xv + bhv;
    __syncthreads();
    if (tid < 64) {
        int uo = tid >> 3, b2 = tid & 7;
        float r = gbuf[uo][b2];
        float f = gbuf[8 + uo][b2];
        float gg = gbuf[16 + uo][b2];
        float o = gbuf[24 + uo][b2];
        float rt = 1.f / (1.f + __expf(-r));
        float ft = 1.f / (1.f + __expf(-f));
        float gt = tanhf(gg);
        float ot = 1.f / (1.f + __expf(-o));
        int bgl = bg * 8 + b2;
        int u = ub * 8 + uo;
        size_t cidx = (size_t)bgl * HH + u;
        float c = (t == 0) ? 0.f : cstate[cidx];
        c = ft * c + rt * gt;
        float h = ot * tanhf(c);
        cstate[cidx] = c;
        hs[((size_t)t * BB + bgl) * HH + u] = h;
    }
}

// ---------------- K3: final_hidden = h @ W_lstm + b_lstm -------------------------
__global__ __launch_bounds__(512) void k3_fh(const float* __restrict__ hs,
                                             const float* __restrict__ Wl,
                                             const float* __restrict__ bl,
                                             float* __restrict__ fh) {
    const int b = blockIdx.x;
    const int j = threadIdx.x;
    __shared__ float hl[512];
    hl[j] = hs[((size_t)(TT - 1) * BB + b) * HH + j];
    __syncthreads();
    float acc = bl[j];
    #pragma unroll 8
    for (int k = 0; k < HH; ++k) acc += hl[k] * Wl[(size_t)k * HH + j];
    fh[(size_t)b * HH + j] = acc;
}

// ---------------- K4: score -> softmax -> att -> output head ---------------------
__global__ __launch_bounds__(256) void k4_att(const float* __restrict__ hs,
                                              const float* __restrict__ fh,
                                              const float* __restrict__ Wa,
                                              const float* __restrict__ ba,
                                              float* __restrict__ out) {
    const int b = blockIdx.x;
    const int tid = threadIdx.x;
    const int lane = tid & 63, w = tid >> 6;
    __shared__ float scores[512];
    __shared__ float attl[512];
    __shared__ float red[8];
    // fh fragment in registers: lane holds fh[b][lane*8 .. +8)
    float fr[8];
    *(float4*)&fr[0] = *(const float4*)&fh[(size_t)b * HH + lane * 8];
    *(float4*)&fr[4] = *(const float4*)&fh[(size_t)b * HH + lane * 8 + 4];
    for (int t = w; t < TT; t += 4) {
        const float* hrow = hs + ((size_t)t * BB + b) * HH + lane * 8;
        float4 h0 = *(const float4*)&hrow[0];
        float4 h1 = *(const float4*)&hrow[4];
        float v = h0.x * fr[0] + h0.y * fr[1] + h0.z * fr[2] + h0.w * fr[3]
                + h1.x * fr[4] + h1.y * fr[5] + h1.z * fr[6] + h1.w * fr[7];
        #pragma unroll
        for (int o = 32; o; o >>= 1) v += __shfl_xor(v, o);
        if (lane == 0) scores[t] = v;
    }
    __syncthreads();
    // softmax over 512
    float s0 = scores[tid], s1 = scores[tid + 256];
    float m = fmaxf(s0, s1);
    #pragma unroll
    for (int o = 32; o; o >>= 1) m = fmaxf(m, __shfl_xor(m, o));
    if (lane == 0) red[w] = m;
    __syncthreads();
    m = fmaxf(fmaxf(red[0], red[1]), fmaxf(red[2], red[3]));
    float e0 = __expf(s0 - m), e1 = __expf(s1 - m);
    float s = e0 + e1;
    #pragma unroll
    for (int o = 32; o; o >>= 1) s += __shfl_xor(s, o);
    if (lane == 0) red[4 + w] = s;
    __syncthreads();
    s = red[4] + red[5] + red[6] + red[7];
    float inv = 1.f / s;
    scores[tid] = e0 * inv;
    scores[tid + 256] = e1 * inv;
    __syncthreads();
    // att[b][j] = sum_t dist[t]*hs[t][b][j]
    float a0 = 0.f, a1 = 0.f;
    for (int t = 0; t < TT; ++t) {
        float d = scores[t];
        const float* hrow = hs + ((size_t)t * BB + b) * HH;
        a0 += d * hrow[tid];
        a1 += d * hrow[tid + 256];
    }
    attl[tid] = a0; attl[tid + 256] = a1;
    // final h -> out[64 + b*512 + j]
    const float* hlast = hs + ((size_t)(TT - 1) * BB + b) * HH;
    out[64 + (size_t)b * HH + tid] = hlast[tid];
    out[64 + (size_t)b * HH + tid + 256] = hlast[tid + 256];
    __syncthreads();
    // out[b] = sigmoid(concat(fh, att) . W_att + b_att)
    float p = fh[(size_t)b * HH + tid] * Wa[tid]
            + fh[(size_t)b * HH + tid + 256] * Wa[tid + 256]
            + attl[tid] * Wa[512 + tid]
            + attl[tid + 256] * Wa[768 + tid];
    #pragma unroll
    for (int o = 32; o; o >>= 1) p += __shfl_xor(p, o);
    if (lane == 0) red[w] = p;
    __syncthreads();
    if (tid == 0) {
        float v = red[0] + red[1] + red[2] + red[3] + ba[0];
        out[b] = 1.f / (1.f + __expf(-v));
    }
}

extern "C" void kernel_launch(void* const* d_in, const int* in_sizes, int n_in,
                              void* d_out, int out_size, void* d_ws, size_t ws_size,
                              hipStream_t stream) {
    const int*   words = (const int*)d_in[0];
    const float* emb   = (const float*)d_in[1];
    const float* Wi    = (const float*)d_in[2];
    const float* bi    = (const float*)d_in[3];
    const float* Wh    = (const float*)d_in[4];
    const float* bh    = (const float*)d_in[5];
    const float* Wl    = (const float*)d_in[6];
    const float* blst  = (const float*)d_in[7];
    const float* Wa    = (const float*)d_in[8];
    const float* ba    = (const float*)d_in[9];
    float* out = (float*)d_out;

    // workspace layout
    char* ws = (char*)d_ws;
    size_t off = 0;
    float* WhT = (float*)(ws + off);            off += (size_t)G4 * HH * 4;          // 4 MB
    __hip_bfloat16* xp = (__hip_bfloat16*)(ws + off); off += (size_t)TT * BB * G4 * 2; // 128 MB
    float* hs = (float*)(ws + off);             off += (size_t)TT * BB * HH * 4;     // 64 MB
    float* cstate = (float*)(ws + off);         off += (size_t)BB * HH * 4;
    float* fh = (float*)(ws + off);             off += (size_t)BB * HH * 4;
    (void)ws_size; (void)in_sizes; (void)n_in; (void)out_size;

    k0_transpose<<<dim3(64, 16), 256, 0, stream>>>(Wh, WhT);
    k1_xp<<<dim3(16, 256), 256, 0, stream>>>(words, emb, Wi, bi, xp);
    for (int t = 0; t < TT; ++t)
        k2_step<<<dim3(64, 8), 256, 0, stream>>>(WhT, xp, bh, hs, cstate, t);
    k3_fh<<<64, 512, 0, stream>>>(hs, Wl, blst, fh);
    k4_att<<<64, 256, 0, stream>>>(hs, fh, Wa, ba, out);
}